// Round 1
// baseline (11391.488 us; speedup 1.0000x reference)
//
#include <hip/hip_runtime.h>
#include <math.h>

#define HWDIM 128
#define IMG   (HWDIM * HWDIM)   // 16384
#define HID   64
#define BATCH 4
#define PLANE (BATCH * HID * IMG)  // 4*64*16384 per-timestep tensor elems

// ---------------- seq conv: 3x3 SAME, Cin=64 -> Cout=64 -------------------
// Block: 256 threads = 16x16 pixel tile. blockIdx.x = b*64 + tileY*8 + tileX.
// blockIdx.y = output-channel group (4 channels each, 16 groups).
__global__ __launch_bounds__(256) void seq_conv_kernel(
    const float* __restrict__ x,    // [B,64,128,128]  (one timestep)
    const float* __restrict__ w,    // [64,64,3,3]
    const float* __restrict__ bias, // [64]
    float* __restrict__ out)        // [B,64,128,128]
{
    __shared__ float tile[8][18][20];
    const int tid = threadIdx.x;
    const int tx = tid & 15, ty = tid >> 4;
    const int tileIdx = blockIdx.x;
    const int b   = tileIdx >> 6;
    const int tyi = (tileIdx >> 3) & 7, txi = tileIdx & 7;
    const int y0 = tyi * 16, x0 = txi * 16;
    const int cog = blockIdx.y;     // 0..15

    float acc0 = 0.f, acc1 = 0.f, acc2 = 0.f, acc3 = 0.f;
    const float* xb = x + (size_t)b * 64 * IMG;

    for (int ci0 = 0; ci0 < 64; ci0 += 8) {
        __syncthreads();
        // stage 8 channels of an 18x18 halo tile
        for (int i = tid; i < 8 * 324; i += 256) {
            int c  = i / 324;
            int r  = i - c * 324;
            int ly = r / 18, lx = r - ly * 18;
            int gy = y0 - 1 + ly, gx = x0 - 1 + lx;
            float v = 0.f;
            if ((unsigned)gy < 128u && (unsigned)gx < 128u)
                v = xb[(size_t)(ci0 + c) * IMG + gy * HWDIM + gx];
            tile[c][ly][lx] = v;
        }
        __syncthreads();
        for (int c = 0; c < 8; ++c) {
            const int ci = ci0 + c;
            const float* wp = w + ((size_t)cog * 4) * 64 * 9 + (size_t)ci * 9;
            #pragma unroll
            for (int dy = 0; dy < 3; ++dy) {
                #pragma unroll
                for (int dx = 0; dx < 3; ++dx) {
                    float v = tile[c][ty + dy][tx + dx];
                    const int tp = dy * 3 + dx;
                    acc0 += v * wp[0 * 64 * 9 + tp];
                    acc1 += v * wp[1 * 64 * 9 + tp];
                    acc2 += v * wp[2 * 64 * 9 + tp];
                    acc3 += v * wp[3 * 64 * 9 + tp];
                }
            }
        }
    }
    const int co = cog * 4;
    const size_t pix = (size_t)(y0 + ty) * HWDIM + (x0 + tx);
    out[((size_t)b * 64 + co + 0) * IMG + pix] = acc0 + bias[co + 0];
    out[((size_t)b * 64 + co + 1) * IMG + pix] = acc1 + bias[co + 1];
    out[((size_t)b * 64 + co + 2) * IMG + pix] = acc2 + bias[co + 2];
    out[((size_t)b * 64 + co + 3) * IMG + pix] = acc3 + bias[co + 3];
}

// ------------- gate conv (Cin=128 -> 256) fused with LSTM update ----------
// blockIdx.y = hid channel ch (0..63); thread computes gates i,f,g,o for ch
// (gate g_j lives at output channel j*64+ch) then the pointwise LSTM update.
__global__ __launch_bounds__(256) void gates_lstm_kernel(
    const float* __restrict__ inp_t, // [B,64,128,128] (seq conv output)
    const float* __restrict__ w,     // [256,128,3,3]
    const float* __restrict__ bias,  // [256]
    const float* __restrict__ h_in,  // [B,64,128,128]
    float* __restrict__ h_out,       // [B,64,128,128]
    float* __restrict__ c)           // [B,64,128,128] in/out (pointwise)
{
    __shared__ float tile[8][18][20];
    const int tid = threadIdx.x;
    const int tx = tid & 15, ty = tid >> 4;
    const int tileIdx = blockIdx.x;
    const int b   = tileIdx >> 6;
    const int tyi = (tileIdx >> 3) & 7, txi = tileIdx & 7;
    const int y0 = tyi * 16, x0 = txi * 16;
    const int ch = blockIdx.y;       // 0..63

    float acc0 = 0.f, acc1 = 0.f, acc2 = 0.f, acc3 = 0.f;

    for (int ci0 = 0; ci0 < 128; ci0 += 8) {
        const float* src = (ci0 < 64)
            ? (inp_t + (size_t)b * 64 * IMG + (size_t)ci0 * IMG)
            : (h_in  + (size_t)b * 64 * IMG + (size_t)(ci0 - 64) * IMG);
        __syncthreads();
        for (int i = tid; i < 8 * 324; i += 256) {
            int cc = i / 324;
            int r  = i - cc * 324;
            int ly = r / 18, lx = r - ly * 18;
            int gy = y0 - 1 + ly, gx = x0 - 1 + lx;
            float v = 0.f;
            if ((unsigned)gy < 128u && (unsigned)gx < 128u)
                v = src[(size_t)cc * IMG + gy * HWDIM + gx];
            tile[cc][ly][lx] = v;
        }
        __syncthreads();
        for (int cc = 0; cc < 8; ++cc) {
            const int ci = ci0 + cc;
            const float* wp = w + (size_t)ch * 128 * 9 + (size_t)ci * 9;
            #pragma unroll
            for (int dy = 0; dy < 3; ++dy) {
                #pragma unroll
                for (int dx = 0; dx < 3; ++dx) {
                    float v = tile[cc][ty + dy][tx + dx];
                    const int tp = dy * 3 + dx;
                    acc0 += v * wp[(size_t)(0 * 64) * 128 * 9 + tp];
                    acc1 += v * wp[(size_t)(1 * 64) * 128 * 9 + tp];
                    acc2 += v * wp[(size_t)(2 * 64) * 128 * 9 + tp];
                    acc3 += v * wp[(size_t)(3 * 64) * 128 * 9 + tp];
                }
            }
        }
    }

    const float gi = acc0 + bias[0 * 64 + ch];
    const float gf = acc1 + bias[1 * 64 + ch];
    const float gg = acc2 + bias[2 * 64 + ch];
    const float go = acc3 + bias[3 * 64 + ch];

    const float si = 1.f / (1.f + __expf(-gi));
    const float sf = 1.f / (1.f + __expf(-gf));
    const float tg = tanhf(gg);
    const float so = 1.f / (1.f + __expf(-go));

    const size_t idx = ((size_t)b * 64 + ch) * IMG + (size_t)(y0 + ty) * HWDIM + (x0 + tx);
    const float c_new = sf * c[idx] + si * tg;
    c[idx] = c_new;
    h_out[idx] = so * tanhf(c_new);
}

extern "C" void kernel_launch(void* const* d_in, const int* in_sizes, int n_in,
                              void* d_out, int out_size, void* d_ws, size_t ws_size,
                              hipStream_t stream) {
    const float* xinp   = (const float*)d_in[0]; // [8,4,64,128,128]
    const float* W_seq  = (const float*)d_in[1]; // [64,64,3,3]
    const float* b_seq  = (const float*)d_in[2]; // [64]
    const float* W_cell = (const float*)d_in[3]; // [256,128,3,3]
    const float* b_cell = (const float*)d_in[4]; // [256]

    float* out     = (float*)d_out;
    float* h_final = out;              // [4,64,128,128]
    float* xout    = out + PLANE;      // [8,4,64,128,128]

    float* cbuf  = (float*)d_ws;       // [4,64,128,128]
    float* hbuf1 = cbuf + PLANE;       // [4,64,128,128]
    float* hbufs[2] = { h_final, hbuf1 };

    const size_t planeBytes = (size_t)PLANE * sizeof(float);
    hipMemsetAsync(h_final, 0, planeBytes, stream);  // h0 = 0 (also final buffer)
    hipMemsetAsync(cbuf,    0, planeBytes, stream);  // c0 = 0

    for (int t = 0; t < 8; ++t) {
        const float* x_t  = xinp + (size_t)t * PLANE;
        float*       in_t = xout + (size_t)t * PLANE;
        seq_conv_kernel<<<dim3(BATCH * 64, 16), 256, 0, stream>>>(
            x_t, W_seq, b_seq, in_t);
        gates_lstm_kernel<<<dim3(BATCH * 64, 64), 256, 0, stream>>>(
            in_t, W_cell, b_cell, hbufs[t & 1], hbufs[(t + 1) & 1], cbuf);
    }
}

// Round 2
// 1263.697 us; speedup vs baseline: 9.0144x; 9.0144x over previous
//
#include <hip/hip_runtime.h>
#include <math.h>

#define HWDIM 128
#define IMG   (HWDIM * HWDIM)       // 16384
#define PLANE (4 * 64 * IMG)        // 4.19M elems (one [B,64,H,W] tensor)

typedef __attribute__((ext_vector_type(8))) short bf16x8;
typedef __attribute__((ext_vector_type(4))) float f32x4;
typedef __attribute__((ext_vector_type(4))) int   i32x4;

__device__ __forceinline__ unsigned short f2bf(float f) {
    unsigned u = __builtin_bit_cast(unsigned, f);
    u += 0x7FFFu + ((u >> 16) & 1u);          // RNE
    return (unsigned short)(u >> 16);
}
__device__ __forceinline__ float bf2f(unsigned short h) {
    unsigned u = ((unsigned)h) << 16;
    return __builtin_bit_cast(float, u);
}
__device__ __forceinline__ float sigmoidf_(float x) {
    return 1.f / (1.f + __expf(-x));
}

// ---- weight prep: W_cell[256][128][3][3] -> Wg2[9][256][128] bf16
//                   W_seq [64][64][3][3]   -> Ws2[9][64][64]   bf16
__global__ void prep_weights_kernel(const float* __restrict__ Wc,
                                    const float* __restrict__ Ws,
                                    unsigned short* __restrict__ Wg2,
                                    unsigned short* __restrict__ Ws2) {
    int i = blockIdx.x * 256 + threadIdx.x;
    if (i < 9 * 256 * 128) {
        int tap = i >> 15, r = i & 32767, co = r >> 7, ci = r & 127;
        Wg2[i] = f2bf(Wc[(co * 128 + ci) * 9 + tap]);
    }
    if (i < 9 * 64 * 64) {
        int tap = i / 4096, r = i & 4095, co = r >> 6, ci = r & 63;
        Ws2[i] = f2bf(Ws[(co * 64 + ci) * 9 + tap]);
    }
}

// ---- seq conv: x fp32 CHW [4][64][128][128] -> xout fp32 CHW + gin bf16 HWC ch0..63
// block: 64 px (one row segment) x 64 couts, 256 threads, 4 waves (2 m-groups x 2 k-groups)
__global__ __launch_bounds__(256) void seq_conv_mfma(
    const float* __restrict__ x,
    const unsigned short* __restrict__ Ws2,   // [9][64][64]
    const float* __restrict__ bseq,           // [64]
    float* __restrict__ xout_t,               // [4][64][128][128]
    unsigned short* __restrict__ gin)         // [4][128][128][128], write ch 0..63
{
    __shared__ unsigned short tile[3 * 66 * 72];   // [ry][xt][ci(pad 72)]
    __shared__ float sbuf[64 * 68];                // [px][co(pad 68)]

    const int tid = threadIdx.x;
    const int bid = blockIdx.x;            // b*256 + y*2 + xhalf
    const int b  = bid >> 8;
    const int y  = (bid >> 1) & 127;
    const int x0 = (bid & 1) * 64;

    // ---- stage input tile (fp32 -> bf16, CHW -> [ry][xt][ci]) ----
    const float* xb = x + (size_t)b * 64 * IMG;
    for (int i = tid; i < 3 * 64 * 64; i += 256) {       // xt in [0,64)
        int xt = i & 63, ci = (i >> 6) & 63, ry = i >> 12;
        int gy = y - 1 + ry, gx = x0 - 1 + xt;
        float v = 0.f;
        if ((unsigned)gy < 128u && (unsigned)gx < 128u)
            v = xb[(size_t)ci * IMG + gy * HWDIM + gx];
        tile[(ry * 66 + xt) * 72 + ci] = f2bf(v);
    }
    for (int i = tid; i < 3 * 64 * 2; i += 256) {        // xt = 64, 65
        int xt = 64 + (i & 1), ci = (i >> 1) & 63, ry = i >> 7;
        int gy = y - 1 + ry, gx = x0 - 1 + xt;
        float v = 0.f;
        if ((unsigned)gy < 128u && (unsigned)gx < 128u)
            v = xb[(size_t)ci * IMG + gy * HWDIM + gx];
        tile[(ry * 66 + xt) * 72 + ci] = f2bf(v);
    }
    __syncthreads();

    const int lane = tid & 63;
    const int w  = tid >> 6;
    const int wm = w & 1;          // cout half base wm*32
    const int wk = w >> 1;         // ci half base wk*32
    const int ln = lane & 15, lg = lane >> 4;

    f32x4 acc[2][4];
    #pragma unroll
    for (int m = 0; m < 2; ++m)
        #pragma unroll
        for (int n = 0; n < 4; ++n) acc[m][n] = (f32x4){0.f, 0.f, 0.f, 0.f};

    const int ci0 = wk * 32;
    for (int tap = 0; tap < 9; ++tap) {
        const int dy = tap / 3, dx = tap % 3;
        bf16x8 a0 = *(const bf16x8*)(Ws2 + (tap * 64 + wm * 32 + ln) * 64 + ci0 + lg * 8);
        bf16x8 a1 = *(const bf16x8*)(Ws2 + (tap * 64 + wm * 32 + 16 + ln) * 64 + ci0 + lg * 8);
        #pragma unroll
        for (int n = 0; n < 4; ++n) {
            bf16x8 bb = *(const bf16x8*)(tile + (dy * 66 + n * 16 + ln + dx) * 72 + ci0 + lg * 8);
            acc[0][n] = __builtin_amdgcn_mfma_f32_16x16x32_bf16(a0, bb, acc[0][n], 0, 0, 0);
            acc[1][n] = __builtin_amdgcn_mfma_f32_16x16x32_bf16(a1, bb, acc[1][n], 0, 0, 0);
        }
    }

    // ---- k-split reduce in sbuf ----
    if (wk == 0) {
        #pragma unroll
        for (int m = 0; m < 2; ++m)
            #pragma unroll
            for (int n = 0; n < 4; ++n)
                #pragma unroll
                for (int r = 0; r < 4; ++r)
                    sbuf[(n * 16 + ln) * 68 + wm * 32 + m * 16 + lg * 4 + r] = acc[m][n][r];
    }
    __syncthreads();
    if (wk == 1) {
        #pragma unroll
        for (int m = 0; m < 2; ++m)
            #pragma unroll
            for (int n = 0; n < 4; ++n)
                #pragma unroll
                for (int r = 0; r < 4; ++r)
                    sbuf[(n * 16 + ln) * 68 + wm * 32 + m * 16 + lg * 4 + r] += acc[m][n][r];
    }
    __syncthreads();

    // ---- epilogue 1: fp32 CHW xout ----
    {
        const int co = tid >> 2, pq = tid & 3;
        const float bsv = bseq[co];
        float* dst = xout_t + ((size_t)b * 64 + co) * IMG + (size_t)y * HWDIM + x0;
        #pragma unroll
        for (int j = 0; j < 16; ++j) {
            int px = pq * 16 + j;
            dst[px] = sbuf[px * 68 + co] + bsv;
        }
    }
    // ---- epilogue 2: bf16 HWC gin (ch 0..63) ----
    {
        const int px = tid >> 2, cg = tid & 3;
        unsigned int pk[8];
        #pragma unroll
        for (int jj = 0; jj < 8; ++jj) {
            int c0 = cg * 16 + jj * 2;
            unsigned short lo = f2bf(sbuf[px * 68 + c0] + bseq[c0]);
            unsigned short hi = f2bf(sbuf[px * 68 + c0 + 1] + bseq[c0 + 1]);
            pk[jj] = (unsigned)lo | ((unsigned)hi << 16);
        }
        unsigned short* dst = gin + ((((size_t)b * 128 + y) * 128) + x0 + px) * 128 + cg * 16;
        i32x4 v0 = { (int)pk[0], (int)pk[1], (int)pk[2], (int)pk[3] };
        i32x4 v1 = { (int)pk[4], (int)pk[5], (int)pk[6], (int)pk[7] };
        *(i32x4*)(dst)     = v0;
        *(i32x4*)(dst + 8) = v1;
    }
}

// ---- gates conv (Cin=128 -> 256) + fused LSTM pointwise
// block: 64 px x 256 couts, 512 threads, 8 waves (4 m-groups x 2 k-groups)
__global__ __launch_bounds__(512) void gates_lstm_mfma(
    const unsigned short* __restrict__ gin,   // [4][128][128][128] (ch0..63 inp, 64..127 h)
    const unsigned short* __restrict__ Wg2,   // [9][256][128]
    const float* __restrict__ bcell,          // [256]
    unsigned short* __restrict__ hout,        // next gin buffer (write ch 64..127) or null
    unsigned short* __restrict__ cbuf,        // [4][128][128][64] bf16, in/out
    float* __restrict__ h32)                  // CHW h_final (t=7) or null
{
    __shared__ __align__(16) unsigned char smem[64 * 260 * 4];   // 66560 B
    unsigned short* tile = (unsigned short*)smem;                // [3][66][136] = 53856 B
    float*          gbuf = (float*)smem;                         // [64][260]

    const int tid = threadIdx.x;
    const int bid = blockIdx.x;
    const int b  = bid >> 8;
    const int y  = (bid >> 1) & 127;
    const int x0 = (bid & 1) * 64;

    // ---- stage [3][66][128ci] bf16 from gin (16B chunks) ----
    const unsigned short* ginb = gin + (size_t)b * 128 * 128 * 128;
    for (int i = tid; i < 3 * 64 * 16; i += 512) {   // xt in [0,64)
        int g = i & 15, xt = (i >> 4) & 63, ry = i >> 10;
        int gy = y - 1 + ry, gx = x0 - 1 + xt;
        i32x4 v = {0, 0, 0, 0};
        if ((unsigned)gy < 128u && (unsigned)gx < 128u)
            v = *(const i32x4*)(ginb + ((size_t)gy * 128 + gx) * 128 + g * 8);
        *(i32x4*)(tile + (ry * 66 + xt) * 136 + g * 8) = v;
    }
    for (int i = tid; i < 3 * 2 * 16; i += 512) {    // xt = 64, 65
        int g = i & 15, xt = 64 + ((i >> 4) & 1), ry = i >> 5;
        int gy = y - 1 + ry, gx = x0 - 1 + xt;
        i32x4 v = {0, 0, 0, 0};
        if ((unsigned)gy < 128u && (unsigned)gx < 128u)
            v = *(const i32x4*)(ginb + ((size_t)gy * 128 + gx) * 128 + g * 8);
        *(i32x4*)(tile + (ry * 66 + xt) * 136 + g * 8) = v;
    }
    __syncthreads();

    const int lane = tid & 63;
    const int wm = (tid >> 6) & 3;      // cout base wm*64
    const int wk = tid >> 8;            // ci base wk*64
    const int ln = lane & 15, lg = lane >> 4;

    f32x4 acc[4][4];
    #pragma unroll
    for (int m = 0; m < 4; ++m)
        #pragma unroll
        for (int n = 0; n < 4; ++n) acc[m][n] = (f32x4){0.f, 0.f, 0.f, 0.f};

    for (int tap = 0; tap < 9; ++tap) {
        const int dy = tap / 3, dx = tap % 3;
        #pragma unroll
        for (int kk = 0; kk < 2; ++kk) {
            const int ci0 = wk * 64 + kk * 32;
            bf16x8 a[4];
            #pragma unroll
            for (int m = 0; m < 4; ++m)
                a[m] = *(const bf16x8*)(Wg2 + ((size_t)(tap * 256 + wm * 64 + m * 16 + ln)) * 128 + ci0 + lg * 8);
            #pragma unroll
            for (int n = 0; n < 4; ++n) {
                bf16x8 bb = *(const bf16x8*)(tile + (dy * 66 + n * 16 + ln + dx) * 136 + ci0 + lg * 8);
                #pragma unroll
                for (int m = 0; m < 4; ++m)
                    acc[m][n] = __builtin_amdgcn_mfma_f32_16x16x32_bf16(a[m], bb, acc[m][n], 0, 0, 0);
            }
        }
    }

    __syncthreads();   // tile dead; gbuf takes over the same LDS

    if (wk == 0) {
        #pragma unroll
        for (int m = 0; m < 4; ++m)
            #pragma unroll
            for (int n = 0; n < 4; ++n)
                #pragma unroll
                for (int r = 0; r < 4; ++r)
                    gbuf[(n * 16 + ln) * 260 + wm * 64 + m * 16 + lg * 4 + r] = acc[m][n][r];
    }
    __syncthreads();
    if (wk == 1) {
        #pragma unroll
        for (int m = 0; m < 4; ++m)
            #pragma unroll
            for (int n = 0; n < 4; ++n)
                #pragma unroll
                for (int r = 0; r < 4; ++r)
                    gbuf[(n * 16 + ln) * 260 + wm * 64 + m * 16 + lg * 4 + r] += acc[m][n][r];
    }
    __syncthreads();

    // ---- fused LSTM pointwise: thread -> (px, 8 channels) ----
    {
        const int px = tid >> 3;         // 0..63
        const int cb = tid & 7;          // channel block
        const int gx2 = x0 + px;
        const size_t cbase = ((((size_t)b * 128 + y) * 128) + gx2) * 64 + cb * 8;
        const size_t hbase = ((((size_t)b * 128 + y) * 128) + gx2) * 128 + 64 + cb * 8;
        float hvals[8];
        unsigned short hb[8], cb16[8];
        #pragma unroll
        for (int j = 0; j < 8; ++j) {
            const int ch = cb * 8 + j;
            float gi = gbuf[px * 260 + ch]        + bcell[ch];
            float gf = gbuf[px * 260 + 64 + ch]   + bcell[64 + ch];
            float gg = gbuf[px * 260 + 128 + ch]  + bcell[128 + ch];
            float go = gbuf[px * 260 + 192 + ch]  + bcell[192 + ch];
            float si = sigmoidf_(gi);
            float sf = sigmoidf_(gf);
            float tg = tanhf(gg);
            float so = sigmoidf_(go);
            float cold = bf2f(cbuf[cbase + j]);
            float cn = sf * cold + si * tg;
            cb16[j] = f2bf(cn);
            hvals[j] = so * tanhf(cn);
            hb[j] = f2bf(hvals[j]);
        }
        #pragma unroll
        for (int j = 0; j < 8; ++j) cbuf[cbase + j] = cb16[j];
        if (hout) {
            #pragma unroll
            for (int j = 0; j < 8; ++j) hout[hbase + j] = hb[j];
        }
        if (h32) {
            #pragma unroll
            for (int j = 0; j < 8; ++j)
                h32[((size_t)b * 64 + cb * 8 + j) * IMG + (size_t)y * HWDIM + gx2] = hvals[j];
        }
    }
}

extern "C" void kernel_launch(void* const* d_in, const int* in_sizes, int n_in,
                              void* d_out, int out_size, void* d_ws, size_t ws_size,
                              hipStream_t stream) {
    const float* xinp   = (const float*)d_in[0]; // [8,4,64,128,128]
    const float* W_seq  = (const float*)d_in[1];
    const float* b_seq  = (const float*)d_in[2];
    const float* W_cell = (const float*)d_in[3];
    const float* b_cell = (const float*)d_in[4];

    float* out     = (float*)d_out;
    float* h_final = out;                    // [4,64,128,128] fp32
    float* xout    = out + PLANE;            // [8,4,64,128,128] fp32

    // ws layout (bf16 elems): c [PLANE] | gin buf1 [2*PLANE] | Wg2 | Ws2  (~25.8 MB)
    unsigned short* cbuf = (unsigned short*)d_ws;
    unsigned short* buf1 = cbuf + PLANE;
    unsigned short* Wg2  = buf1 + (size_t)2 * PLANE;
    unsigned short* Ws2  = Wg2 + 9 * 256 * 128;

    // gin buf0 overlays the h_final region of d_out (2*PLANE bf16 == PLANE fp32 bytes)
    unsigned short* buf0 = (unsigned short*)d_out;
    unsigned short* gbufs[2] = { buf0, buf1 };

    hipMemsetAsync(buf0, 0, (size_t)2 * PLANE * sizeof(unsigned short), stream); // h0 = 0
    hipMemsetAsync(cbuf, 0, (size_t)PLANE * sizeof(unsigned short), stream);     // c0 = 0

    prep_weights_kernel<<<1152, 256, 0, stream>>>(W_cell, W_seq, Wg2, Ws2);

    for (int t = 0; t < 8; ++t) {
        const float* x_t    = xinp + (size_t)t * PLANE;
        float*       xout_t = xout + (size_t)t * PLANE;
        seq_conv_mfma<<<1024, 256, 0, stream>>>(x_t, Ws2, b_seq, xout_t, gbufs[t & 1]);
        gates_lstm_mfma<<<1024, 512, 0, stream>>>(
            gbufs[t & 1], Wg2, b_cell,
            (t < 7) ? gbufs[(t + 1) & 1] : (unsigned short*)nullptr,
            cbuf,
            (t == 7) ? h_final : (float*)nullptr);
    }
}

// Round 4
// 953.078 us; speedup vs baseline: 11.9523x; 1.3259x over previous
//
#include <hip/hip_runtime.h>
#include <math.h>

#define HWDIM 128
#define IMG   (HWDIM * HWDIM)       // 16384
#define PLANE (4 * 64 * IMG)        // elems of one [B,64,H,W] tensor

typedef __attribute__((ext_vector_type(8))) short bf16x8;
typedef __attribute__((ext_vector_type(4))) float f32x4;
typedef __attribute__((ext_vector_type(4))) int   i32x4;

__device__ __forceinline__ unsigned short f2bf(float f) {
    unsigned u = __builtin_bit_cast(unsigned, f);
    u += 0x7FFFu + ((u >> 16) & 1u);          // RNE
    return (unsigned short)(u >> 16);
}
__device__ __forceinline__ float bf2f(unsigned short h) {
    unsigned u = ((unsigned)h) << 16;
    return __builtin_bit_cast(float, u);
}
__device__ __forceinline__ float sigmoidf_(float x) {
    return 1.f / (1.f + __expf(-x));
}
__device__ __forceinline__ float tanhf_(float x) {
    return 1.f - 2.f / (__expf(2.f * x) + 1.f);
}

// ---- weight prep: W_cell[256][128][3][3] -> Wg2[9][256][128] bf16
//                   W_seq [64][64][3][3]   -> Ws2[9][64][64]   bf16
__global__ void prep_weights_kernel(const float* __restrict__ Wc,
                                    const float* __restrict__ Ws,
                                    unsigned short* __restrict__ Wg2,
                                    unsigned short* __restrict__ Ws2) {
    int i = blockIdx.x * 256 + threadIdx.x;
    if (i < 9 * 256 * 128) {
        int tap = i >> 15, r = i & 32767, co = r >> 7, ci = r & 127;
        Wg2[i] = f2bf(Wc[(co * 128 + ci) * 9 + tap]);
    }
    if (i < 9 * 64 * 64) {
        int tap = i / 4096, r = i & 4095, co = r >> 6, ci = r & 63;
        Ws2[i] = f2bf(Ws[(co * 64 + ci) * 9 + tap]);
    }
}

// ---- seq conv: x fp32 CHW -> xout fp32 CHW + gin bf16 HWC (ch 0..63)
// 256 threads / 4 waves. Block = 64 px (half row) x 64 couts, K=64.
// Wave w owns couts w*16..w*16+15 (one m-frag), all 4 n-frags, full K.
__global__ __launch_bounds__(256) void seq_conv_mfma(
    const float* __restrict__ x,
    const unsigned short* __restrict__ Ws2,   // [9][64][64]
    const float* __restrict__ bseq,           // [64]
    float* __restrict__ xout_t,               // [4][64][128][128]
    unsigned short* __restrict__ gin)         // [4][128][128][128], ch 0..63
{
    __shared__ __align__(16) unsigned short tile[3 * 66 * 72];  // 28512 B
    __shared__ float sbuf[64 * 68];                             // 17408 B

    const int tid = threadIdx.x;
    const int bid = blockIdx.x;            // b*256 + y*2 + xhalf
    const int b  = bid >> 8;
    const int y  = (bid >> 1) & 127;
    const int x0 = (bid & 1) * 64;

    const float* xb = x + (size_t)b * 64 * IMG;

    // main staging: aligned float4 pairs, xt = 1..64.  i=((ry*32+cip)*16+xq)
    for (int i = tid; i < 1536; i += 256) {
        int xq = i & 15, cip = (i >> 4) & 31, ry = i >> 9;
        int gy = y - 1 + ry;
        int gxs = x0 + xq * 4;
        int ci = cip * 2;
        float4 va = {0.f, 0.f, 0.f, 0.f}, vb = {0.f, 0.f, 0.f, 0.f};
        if ((unsigned)gy < 128u) {
            va = *(const float4*)(xb + (size_t)ci * IMG + gy * HWDIM + gxs);
            vb = *(const float4*)(xb + (size_t)(ci + 1) * IMG + gy * HWDIM + gxs);
        }
        const float* pa = (const float*)&va;
        const float* pb = (const float*)&vb;
        #pragma unroll
        for (int j = 0; j < 4; ++j) {
            unsigned pk = (unsigned)f2bf(pa[j]) | ((unsigned)f2bf(pb[j]) << 16);
            *(unsigned*)(tile + (ry * 66 + 1 + xq * 4 + j) * 72 + ci) = pk;
        }
    }
    // edge staging: xt = 0 and 65.  i=((ry*32+cip)*2+e)
    for (int i = tid; i < 192; i += 256) {
        int e = i & 1, cip = (i >> 1) & 31, ry = i >> 6;
        int xt = e ? 65 : 0;
        int gy = y - 1 + ry, gx = x0 - 1 + xt;
        int ci = cip * 2;
        float a = 0.f, b2 = 0.f;
        if ((unsigned)gy < 128u && (unsigned)gx < 128u) {
            a  = xb[(size_t)ci * IMG + gy * HWDIM + gx];
            b2 = xb[(size_t)(ci + 1) * IMG + gy * HWDIM + gx];
        }
        unsigned pk = (unsigned)f2bf(a) | ((unsigned)f2bf(b2) << 16);
        *(unsigned*)(tile + (ry * 66 + xt) * 72 + ci) = pk;
    }
    __syncthreads();

    const int lane = tid & 63;
    const int w = tid >> 6;                 // cout stripe w*16
    const int ln = lane & 15, lg = lane >> 4;

    f32x4 acc[4];
    #pragma unroll
    for (int n = 0; n < 4; ++n) acc[n] = (f32x4){0.f, 0.f, 0.f, 0.f};

    for (int tap = 0; tap < 9; ++tap) {
        const int dy = tap / 3, dx = tap % 3;
        #pragma unroll
        for (int kk = 0; kk < 2; ++kk) {
            bf16x8 wf = *(const bf16x8*)(Ws2 + (tap * 64 + w * 16 + ln) * 64 + kk * 32 + lg * 8);
            #pragma unroll
            for (int n = 0; n < 4; ++n) {
                bf16x8 imf = *(const bf16x8*)(tile + (dy * 66 + n * 16 + ln + dx) * 72 + kk * 32 + lg * 8);
                acc[n] = __builtin_amdgcn_mfma_f32_16x16x32_bf16(wf, imf, acc[n], 0, 0, 0);
            }
        }
    }

    // epilogue 1: xout fp32 CHW, coalesced (lane -> px)
    const int co = w * 16 + lg * 4;
    #pragma unroll
    for (int r = 0; r < 4; ++r) {
        const float bv = bseq[co + r];
        float* dst = xout_t + ((size_t)b * 64 + co + r) * IMG + (size_t)y * HWDIM + x0;
        #pragma unroll
        for (int n = 0; n < 4; ++n)
            dst[n * 16 + ln] = acc[n][r] + bv;
    }

    // epilogue 2: gin bf16 HWC via LDS bounce
    #pragma unroll
    for (int n = 0; n < 4; ++n)
        #pragma unroll
        for (int r = 0; r < 4; ++r)
            sbuf[(n * 16 + ln) * 68 + co + r] = acc[n][r];
    __syncthreads();
    {
        const int px = tid >> 2, cg = tid & 3;
        unsigned pk[8];
        #pragma unroll
        for (int jj = 0; jj < 8; ++jj) {
            int c0 = cg * 16 + jj * 2;
            unsigned short lo = f2bf(sbuf[px * 68 + c0] + bseq[c0]);
            unsigned short hi = f2bf(sbuf[px * 68 + c0 + 1] + bseq[c0 + 1]);
            pk[jj] = (unsigned)lo | ((unsigned)hi << 16);
        }
        unsigned short* dst = gin + ((((size_t)b * 128 + y) * 128) + x0 + px) * 128 + cg * 16;
        i32x4 v0 = { (int)pk[0], (int)pk[1], (int)pk[2], (int)pk[3] };
        i32x4 v1 = { (int)pk[4], (int)pk[5], (int)pk[6], (int)pk[7] };
        *(i32x4*)(dst)     = v0;
        *(i32x4*)(dst + 8) = v1;
    }
}

// ---- gates conv (Cin=128 -> 256 gate-striped) + in-register LSTM epilogue
// 256 threads / 4 waves. Block = 64 px x 256 couts, full K=128 per wave.
// Wave w owns couts {g*64 + w*16 + ln : g in 0..3} -> each lane holds all 4
// gates for its (px, ch) in acc -> pointwise LSTM with no LDS reduce.
__global__ __launch_bounds__(256) void gates_lstm_mfma(
    const unsigned short* __restrict__ gin,   // [4][128][128][128]
    const unsigned short* __restrict__ Wg2,   // [9][256][128]
    const float* __restrict__ bcell,          // [256]
    unsigned short* __restrict__ hout,        // next gin (ch 64..127) or null
    unsigned short* __restrict__ cbuf,        // [4][128][128][64] bf16 in/out
    float* __restrict__ h32)                  // h_final fp32 CHW (t=7) or null
{
    __shared__ __align__(16) unsigned short tile[3 * 66 * 136];  // 53856 B

    const int tid = threadIdx.x;
    const int bid = blockIdx.x;
    const int b  = bid >> 8;
    const int y  = (bid >> 1) & 127;
    const int x0 = (bid & 1) * 64;

    const unsigned short* ginb = gin + (size_t)b * 128 * 128 * 128;
    for (int i = tid; i < 3 * 64 * 16; i += 256) {   // xt 0..63
        int g = i & 15, xt = (i >> 4) & 63, ry = i >> 10;
        int gy = y - 1 + ry, gx = x0 - 1 + xt;
        i32x4 v = {0, 0, 0, 0};
        if ((unsigned)gy < 128u && (unsigned)gx < 128u)
            v = *(const i32x4*)(ginb + ((size_t)gy * 128 + gx) * 128 + g * 8);
        *(i32x4*)(tile + (ry * 66 + xt) * 136 + g * 8) = v;
    }
    for (int i = tid; i < 3 * 2 * 16; i += 256) {    // xt = 64, 65
        int g = i & 15, xt = 64 + ((i >> 4) & 1), ry = i >> 5;
        int gy = y - 1 + ry, gx = x0 - 1 + xt;
        i32x4 v = {0, 0, 0, 0};
        if ((unsigned)gy < 128u && (unsigned)gx < 128u)
            v = *(const i32x4*)(ginb + ((size_t)gy * 128 + gx) * 128 + g * 8);
        *(i32x4*)(tile + (ry * 66 + xt) * 136 + g * 8) = v;
    }
    __syncthreads();

    const int lane = tid & 63;
    const int w = tid >> 6;                 // cout stripe (within each gate)
    const int ln = lane & 15, lg = lane >> 4;
    const int s = w * 16;

    f32x4 acc[4][4];                        // [m_px][gate]
    #pragma unroll
    for (int m = 0; m < 4; ++m)
        #pragma unroll
        for (int g = 0; g < 4; ++g) acc[m][g] = (f32x4){0.f, 0.f, 0.f, 0.f};

    for (int tap = 0; tap < 9; ++tap) {
        const int dy = tap / 3, dx = tap % 3;
        #pragma unroll
        for (int kk = 0; kk < 4; ++kk) {
            bf16x8 wf[4];
            #pragma unroll
            for (int g = 0; g < 4; ++g)
                wf[g] = *(const bf16x8*)(Wg2 + ((size_t)(tap * 256 + g * 64 + s + ln)) * 128 + kk * 32 + lg * 8);
            #pragma unroll
            for (int m = 0; m < 4; ++m) {
                bf16x8 af = *(const bf16x8*)(tile + (dy * 66 + m * 16 + ln + dx) * 136 + kk * 32 + lg * 8);
                #pragma unroll
                for (int g = 0; g < 4; ++g)
                    acc[m][g] = __builtin_amdgcn_mfma_f32_16x16x32_bf16(af, wf[g], acc[m][g], 0, 0, 0);
            }
        }
    }

    // in-register LSTM pointwise: lane owns ch = s + ln, px = m*16 + lg*4 + r
    const int ch = s + ln;
    const float bi = bcell[ch], bf_ = bcell[64 + ch];
    const float bg = bcell[128 + ch], bo = bcell[192 + ch];

    #pragma unroll
    for (int m = 0; m < 4; ++m) {
        #pragma unroll
        for (int r = 0; r < 4; ++r) {
            const int px = m * 16 + lg * 4 + r;
            float gi = acc[m][0][r] + bi;
            float gf = acc[m][1][r] + bf_;
            float gg = acc[m][2][r] + bg;
            float go = acc[m][3][r] + bo;
            float si = sigmoidf_(gi);
            float sf = sigmoidf_(gf);
            float tg = tanhf_(gg);
            float so = sigmoidf_(go);
            const size_t pixbase = ((size_t)b * 128 + y) * 128 + x0 + px;
            const size_t cidx = pixbase * 64 + ch;
            float cold = bf2f(cbuf[cidx]);
            float cn = sf * cold + si * tg;
            cbuf[cidx] = f2bf(cn);
            float hv = so * tanhf_(cn);
            if (hout) hout[pixbase * 128 + 64 + ch] = f2bf(hv);
            if (h32)  h32[((size_t)b * 64 + ch) * IMG + (size_t)y * HWDIM + x0 + px] = hv;
        }
    }
}

extern "C" void kernel_launch(void* const* d_in, const int* in_sizes, int n_in,
                              void* d_out, int out_size, void* d_ws, size_t ws_size,
                              hipStream_t stream) {
    const float* xinp   = (const float*)d_in[0]; // [8,4,64,128,128]
    const float* W_seq  = (const float*)d_in[1];
    const float* b_seq  = (const float*)d_in[2];
    const float* W_cell = (const float*)d_in[3];
    const float* b_cell = (const float*)d_in[4];

    float* out     = (float*)d_out;
    float* h_final = out;                    // [4,64,128,128] fp32
    float* xout    = out + PLANE;            // [8,4,64,128,128] fp32

    // ws (bf16 elems): c [PLANE] | gin buf1 [2*PLANE] | Wg2 | Ws2
    unsigned short* cbuf = (unsigned short*)d_ws;
    unsigned short* buf1 = cbuf + PLANE;
    unsigned short* Wg2  = buf1 + (size_t)2 * PLANE;
    unsigned short* Ws2  = Wg2 + 9 * 256 * 128;

    // gin buf0 overlays the h_final slot of d_out
    unsigned short* buf0 = (unsigned short*)d_out;
    unsigned short* gbufs[2] = { buf0, buf1 };

    hipMemsetAsync(buf0, 0, (size_t)2 * PLANE * sizeof(unsigned short), stream); // h0
    hipMemsetAsync(cbuf, 0, (size_t)PLANE * sizeof(unsigned short), stream);     // c0

    prep_weights_kernel<<<1152, 256, 0, stream>>>(W_cell, W_seq, Wg2, Ws2);

    for (int t = 0; t < 8; ++t) {
        const float* x_t    = xinp + (size_t)t * PLANE;
        float*       xout_t = xout + (size_t)t * PLANE;
        seq_conv_mfma<<<1024, 256, 0, stream>>>(x_t, Ws2, b_seq, xout_t, gbufs[t & 1]);
        gates_lstm_mfma<<<1024, 256, 0, stream>>>(
            gbufs[t & 1], Wg2, b_cell,
            (t < 7) ? gbufs[(t + 1) & 1] : (unsigned short*)nullptr,
            cbuf,
            (t == 7) ? h_final : (float*)nullptr);
    }
}

// Round 5
// 868.965 us; speedup vs baseline: 13.1093x; 1.0968x over previous
//
#include <hip/hip_runtime.h>
#include <math.h>

#define HWDIM 128
#define IMG   (HWDIM * HWDIM)       // 16384
#define PLANE (4 * 64 * IMG)        // elems of one [B,64,H,W] tensor

typedef __attribute__((ext_vector_type(8))) short bf16x8;
typedef __attribute__((ext_vector_type(4))) float f32x4;
typedef __attribute__((ext_vector_type(4))) int   i32x4;

__device__ __forceinline__ unsigned short f2bf(float f) {
    unsigned u = __builtin_bit_cast(unsigned, f);
    u += 0x7FFFu + ((u >> 16) & 1u);          // RNE
    return (unsigned short)(u >> 16);
}
__device__ __forceinline__ float bf2f(unsigned short h) {
    unsigned u = ((unsigned)h) << 16;
    return __builtin_bit_cast(float, u);
}
__device__ __forceinline__ float sigmoidf_(float x) {
    return 1.f / (1.f + __expf(-x));
}
__device__ __forceinline__ float tanhf_(float x) {
    return 1.f - 2.f / (__expf(2.f * x) + 1.f);
}

// ---- weight prep: W_cell[256][128][3][3] -> Wg2[9][256][128] bf16
//                   W_seq [64][64][3][3]   -> Ws2[9][64][64]   bf16
__global__ void prep_weights_kernel(const float* __restrict__ Wc,
                                    const float* __restrict__ Ws,
                                    unsigned short* __restrict__ Wg2,
                                    unsigned short* __restrict__ Ws2) {
    int i = blockIdx.x * 256 + threadIdx.x;
    if (i < 9 * 256 * 128) {
        int tap = i >> 15, r = i & 32767, co = r >> 7, ci = r & 127;
        Wg2[i] = f2bf(Wc[(co * 128 + ci) * 9 + tap]);
    }
    if (i < 9 * 64 * 64) {
        int tap = i / 4096, r = i & 4095, co = r >> 6, ci = r & 63;
        Ws2[i] = f2bf(Ws[(co * 64 + ci) * 9 + tap]);
    }
}

// ---- seq conv: x fp32 CHW -> xout fp32 CHW + gin bf16 HWC (ch 0..63)
// 256 threads / 4 waves. Block = 64 px (half row) x 64 couts, K=64.
__global__ __launch_bounds__(256) void seq_conv_mfma(
    const float* __restrict__ x,
    const unsigned short* __restrict__ Ws2,   // [9][64][64]
    const float* __restrict__ bseq,           // [64]
    float* __restrict__ xout_t,               // [4][64][128][128]
    unsigned short* __restrict__ gin)         // [4][128][128][128], ch 0..63
{
    // union: tile (staging+compute) then sbuf (epilogue) — barrier-separated
    __shared__ __align__(16) unsigned char smem[3 * 66 * 72 * 2];  // 28512 B
    unsigned short* tile = (unsigned short*)smem;                  // [3][66][72]
    float*          sbuf = (float*)smem;                           // [64][68]

    const int tid = threadIdx.x;
    const int bid = blockIdx.x;            // b*256 + y*2 + xhalf
    const int b  = bid >> 8;
    const int y  = (bid >> 1) & 127;
    const int x0 = (bid & 1) * 64;

    const float* xb = x + (size_t)b * 64 * IMG;

    // ---- two-phase staging: issue all loads, then ds_write ----
    float4 fa[6], fb[6];
    #pragma unroll
    for (int it = 0; it < 6; ++it) {
        int i = tid + it * 256;
        int xq = i & 15, cip = (i >> 4) & 31, ry = i >> 9;
        int gy = y - 1 + ry;
        int ci = cip * 2;
        float4 va = {0.f, 0.f, 0.f, 0.f}, vb = {0.f, 0.f, 0.f, 0.f};
        if ((unsigned)gy < 128u) {
            va = *(const float4*)(xb + (size_t)ci * IMG + gy * HWDIM + x0 + xq * 4);
            vb = *(const float4*)(xb + (size_t)(ci + 1) * IMG + gy * HWDIM + x0 + xq * 4);
        }
        fa[it] = va; fb[it] = vb;
    }
    float ea = 0.f, eb = 0.f;
    {
        int e = tid & 1, cip = (tid >> 1) & 31, ry = tid >> 6;
        int xt = e ? 65 : 0;
        int gy = y - 1 + ry, gx = x0 - 1 + xt;
        int ci = cip * 2;
        if (tid < 192 && (unsigned)gy < 128u && (unsigned)gx < 128u) {
            ea = xb[(size_t)ci * IMG + gy * HWDIM + gx];
            eb = xb[(size_t)(ci + 1) * IMG + gy * HWDIM + gx];
        }
    }
    #pragma unroll
    for (int it = 0; it < 6; ++it) {
        int i = tid + it * 256;
        int xq = i & 15, cip = (i >> 4) & 31, ry = i >> 9;
        int ci = cip * 2;
        const float* pa = (const float*)&fa[it];
        const float* pb = (const float*)&fb[it];
        #pragma unroll
        for (int j = 0; j < 4; ++j) {
            unsigned pk = (unsigned)f2bf(pa[j]) | ((unsigned)f2bf(pb[j]) << 16);
            *(unsigned*)(tile + (ry * 66 + 1 + xq * 4 + j) * 72 + ci) = pk;
        }
    }
    if (tid < 192) {
        int e = tid & 1, cip = (tid >> 1) & 31, ry = tid >> 6;
        int xt = e ? 65 : 0;
        unsigned pk = (unsigned)f2bf(ea) | ((unsigned)f2bf(eb) << 16);
        *(unsigned*)(tile + (ry * 66 + xt) * 72 + cip * 2) = pk;
    }
    __syncthreads();

    const int lane = tid & 63;
    const int w = tid >> 6;                 // cout stripe w*16
    const int ln = lane & 15, lg = lane >> 4;

    f32x4 acc[4];
    #pragma unroll
    for (int n = 0; n < 4; ++n) acc[n] = (f32x4){0.f, 0.f, 0.f, 0.f};

    // ---- MFMA loop, double-buffered weight loads (18 steps = 9 tap x 2 kk) ----
    const unsigned short* wbase = Ws2 + (size_t)(w * 16 + ln) * 64 + lg * 8;
    auto WL = [&](int step) -> bf16x8 {
        int tap = step >> 1, kk = step & 1;
        return *(const bf16x8*)(wbase + tap * 4096 + kk * 32);
    };
    auto MS = [&](bf16x8 wf, int step) {
        int tap = step >> 1, kk = step & 1;
        int dy = tap / 3, dxx = tap % 3;
        #pragma unroll
        for (int n = 0; n < 4; ++n) {
            bf16x8 imf = *(const bf16x8*)(tile + (dy * 66 + n * 16 + ln + dxx) * 72 + kk * 32 + lg * 8);
            acc[n] = __builtin_amdgcn_mfma_f32_16x16x32_bf16(wf, imf, acc[n], 0, 0, 0);
        }
    };
    bf16x8 wA = WL(0), wB;
    #pragma unroll
    for (int st = 0; st < 18; st += 2) {
        wB = WL(st + 1);
        MS(wA, st);
        if (st + 2 < 18) wA = WL(st + 2);
        MS(wB, st + 1);
    }

    // epilogue 1: xout fp32 CHW, coalesced (lane -> px)
    const int co = w * 16 + lg * 4;
    #pragma unroll
    for (int r = 0; r < 4; ++r) {
        const float bv = bseq[co + r];
        float* dst = xout_t + ((size_t)b * 64 + co + r) * IMG + (size_t)y * HWDIM + x0;
        #pragma unroll
        for (int n = 0; n < 4; ++n)
            dst[n * 16 + ln] = acc[n][r] + bv;
    }

    __syncthreads();   // tile dead; sbuf takes over the same LDS

    // epilogue 2: gin bf16 HWC via LDS bounce
    #pragma unroll
    for (int n = 0; n < 4; ++n)
        #pragma unroll
        for (int r = 0; r < 4; ++r)
            sbuf[(n * 16 + ln) * 68 + co + r] = acc[n][r];
    __syncthreads();
    {
        const int px = tid >> 2, cg = tid & 3;
        unsigned pk[8];
        #pragma unroll
        for (int jj = 0; jj < 8; ++jj) {
            int c0 = cg * 16 + jj * 2;
            unsigned short lo = f2bf(sbuf[px * 68 + c0] + bseq[c0]);
            unsigned short hi = f2bf(sbuf[px * 68 + c0 + 1] + bseq[c0 + 1]);
            pk[jj] = (unsigned)lo | ((unsigned)hi << 16);
        }
        unsigned short* dst = gin + ((((size_t)b * 128 + y) * 128) + x0 + px) * 128 + cg * 16;
        i32x4 v0 = { (int)pk[0], (int)pk[1], (int)pk[2], (int)pk[3] };
        i32x4 v1 = { (int)pk[4], (int)pk[5], (int)pk[6], (int)pk[7] };
        *(i32x4*)(dst)     = v0;
        *(i32x4*)(dst + 8) = v1;
    }
}

// ---- gates conv (Cin=128 -> 256 gate-striped) + in-register LSTM epilogue
// 256 threads / 4 waves. Wave w owns couts {g*64 + w*16 + ln}; each lane holds
// all 4 gates for its (px, ch) in acc -> pointwise LSTM with no LDS reduce.
__global__ __launch_bounds__(256) void gates_lstm_mfma(
    const unsigned short* __restrict__ gin,   // [4][128][128][128]
    const unsigned short* __restrict__ Wg2,   // [9][256][128]
    const float* __restrict__ bcell,          // [256]
    unsigned short* __restrict__ hout,        // next gin (ch 64..127) or null
    unsigned short* __restrict__ cbuf,        // [4][128][128][64] bf16 in/out
    float* __restrict__ h32)                  // h_final fp32 CHW (t=7) or null
{
    __shared__ __align__(16) unsigned short tile[3 * 66 * 136];  // 53856 B

    const int tid = threadIdx.x;
    const int bid = blockIdx.x;
    const int b  = bid >> 8;
    const int y  = (bid >> 1) & 127;
    const int x0 = (bid & 1) * 64;

    const unsigned short* ginb = gin + (size_t)b * 128 * 128 * 128;

    // ---- two-phase staging: 12 main + 1 edge loads in flight, then ds_write ----
    i32x4 sv[12];
    #pragma unroll
    for (int it = 0; it < 12; ++it) {
        int i = tid + it * 256;
        int g = i & 15, xt = (i >> 4) & 63, ry = i >> 10;
        int gy = y - 1 + ry, gx = x0 - 1 + xt;
        i32x4 v = {0, 0, 0, 0};
        if ((unsigned)gy < 128u && (unsigned)gx < 128u)
            v = *(const i32x4*)(ginb + ((size_t)gy * 128 + gx) * 128 + g * 8);
        sv[it] = v;
    }
    i32x4 ev = {0, 0, 0, 0};
    {
        int g = tid & 15, xt = 64 + ((tid >> 4) & 1), ry = tid >> 5;
        int gy = y - 1 + ry, gx = x0 - 1 + xt;
        if (tid < 96 && (unsigned)gy < 128u && (unsigned)gx < 128u)
            ev = *(const i32x4*)(ginb + ((size_t)gy * 128 + gx) * 128 + g * 8);
    }
    #pragma unroll
    for (int it = 0; it < 12; ++it) {
        int i = tid + it * 256;
        int g = i & 15, xt = (i >> 4) & 63, ry = i >> 10;
        *(i32x4*)(tile + (ry * 66 + xt) * 136 + g * 8) = sv[it];
    }
    if (tid < 96) {
        int g = tid & 15, xt = 64 + ((tid >> 4) & 1), ry = tid >> 5;
        *(i32x4*)(tile + (ry * 66 + xt) * 136 + g * 8) = ev;
    }
    __syncthreads();

    const int lane = tid & 63;
    const int w = tid >> 6;                 // cout stripe (within each gate)
    const int ln = lane & 15, lg = lane >> 4;
    const int s = w * 16;

    f32x4 acc[4][4];                        // [m_px][gate]
    #pragma unroll
    for (int m = 0; m < 4; ++m)
        #pragma unroll
        for (int g = 0; g < 4; ++g) acc[m][g] = (f32x4){0.f, 0.f, 0.f, 0.f};

    // ---- MFMA loop: 36 steps (9 tap x 4 kk), double-buffered weights ----
    const unsigned short* wbase = Wg2 + (size_t)(s + ln) * 128 + lg * 8;
    // offset(step) = tap*256*128 + g*64*128 + kk*32
    auto WLOAD = [&](bf16x8* dst, int step) {
        const int tap = step >> 2, kk = step & 3;
        #pragma unroll
        for (int g = 0; g < 4; ++g)
            dst[g] = *(const bf16x8*)(wbase + tap * 32768 + g * 8192 + kk * 32);
    };
    auto MSTEP = [&](const bf16x8* wf, int step) {
        const int tap = step >> 2, kk = step & 3;
        const int dy = tap / 3, dxx = tap % 3;
        #pragma unroll
        for (int m = 0; m < 4; ++m) {
            bf16x8 af = *(const bf16x8*)(tile + (dy * 66 + m * 16 + ln + dxx) * 136 + kk * 32 + lg * 8);
            #pragma unroll
            for (int g = 0; g < 4; ++g)
                acc[m][g] = __builtin_amdgcn_mfma_f32_16x16x32_bf16(af, wf[g], acc[m][g], 0, 0, 0);
        }
    };

    bf16x8 wfA[4], wfB[4];
    WLOAD(wfA, 0);
    #pragma unroll
    for (int st = 0; st < 36; st += 2) {
        WLOAD(wfB, st + 1);
        MSTEP(wfA, st);
        if (st + 2 < 36) WLOAD(wfA, st + 2);
        MSTEP(wfB, st + 1);
    }

    // in-register LSTM pointwise: lane owns ch = s + ln, px = m*16 + lg*4 + r
    const int ch = s + ln;
    const float bi = bcell[ch], bf_ = bcell[64 + ch];
    const float bg = bcell[128 + ch], bo = bcell[192 + ch];

    #pragma unroll
    for (int m = 0; m < 4; ++m) {
        #pragma unroll
        for (int r = 0; r < 4; ++r) {
            const int px = m * 16 + lg * 4 + r;
            float gi = acc[m][0][r] + bi;
            float gf = acc[m][1][r] + bf_;
            float gg = acc[m][2][r] + bg;
            float go = acc[m][3][r] + bo;
            float si = sigmoidf_(gi);
            float sf = sigmoidf_(gf);
            float tg = tanhf_(gg);
            float so = sigmoidf_(go);
            const size_t pixbase = ((size_t)b * 128 + y) * 128 + x0 + px;
            const size_t cidx = pixbase * 64 + ch;
            float cold = bf2f(cbuf[cidx]);
            float cn = sf * cold + si * tg;
            cbuf[cidx] = f2bf(cn);
            float hv = so * tanhf_(cn);
            if (hout) hout[pixbase * 128 + 64 + ch] = f2bf(hv);
            if (h32)  h32[((size_t)b * 64 + ch) * IMG + (size_t)y * HWDIM + x0 + px] = hv;
        }
    }
}

extern "C" void kernel_launch(void* const* d_in, const int* in_sizes, int n_in,
                              void* d_out, int out_size, void* d_ws, size_t ws_size,
                              hipStream_t stream) {
    const float* xinp   = (const float*)d_in[0]; // [8,4,64,128,128]
    const float* W_seq  = (const float*)d_in[1];
    const float* b_seq  = (const float*)d_in[2];
    const float* W_cell = (const float*)d_in[3];
    const float* b_cell = (const float*)d_in[4];

    float* out     = (float*)d_out;
    float* h_final = out;                    // [4,64,128,128] fp32
    float* xout    = out + PLANE;            // [8,4,64,128,128] fp32

    // ws (bf16 elems): c [PLANE] | gin buf1 [2*PLANE] | Wg2 | Ws2
    unsigned short* cbuf = (unsigned short*)d_ws;
    unsigned short* buf1 = cbuf + PLANE;
    unsigned short* Wg2  = buf1 + (size_t)2 * PLANE;
    unsigned short* Ws2  = Wg2 + 9 * 256 * 128;

    // gin buf0 overlays the h_final slot of d_out
    unsigned short* buf0 = (unsigned short*)d_out;
    unsigned short* gbufs[2] = { buf0, buf1 };

    hipMemsetAsync(buf0, 0, (size_t)2 * PLANE * sizeof(unsigned short), stream); // h0
    hipMemsetAsync(cbuf, 0, (size_t)PLANE * sizeof(unsigned short), stream);     // c0

    prep_weights_kernel<<<1152, 256, 0, stream>>>(W_cell, W_seq, Wg2, Ws2);

    for (int t = 0; t < 8; ++t) {
        const float* x_t    = xinp + (size_t)t * PLANE;
        float*       xout_t = xout + (size_t)t * PLANE;
        seq_conv_mfma<<<1024, 256, 0, stream>>>(x_t, Ws2, b_seq, xout_t, gbufs[t & 1]);
        gates_lstm_mfma<<<1024, 256, 0, stream>>>(
            gbufs[t & 1], Wg2, b_cell,
            (t < 7) ? gbufs[(t + 1) & 1] : (unsigned short*)nullptr,
            cbuf,
            (t == 7) ? h_final : (float*)nullptr);
    }
}

// Round 7
// 809.429 us; speedup vs baseline: 14.0735x; 1.0736x over previous
//
#include <hip/hip_runtime.h>
#include <math.h>

#define HWDIM 128
#define IMG   (HWDIM * HWDIM)       // 16384
#define PLANE (4 * 64 * IMG)        // elems of one [B,64,H,W] tensor

typedef __attribute__((ext_vector_type(8))) short bf16x8;
typedef __attribute__((ext_vector_type(4))) float f32x4;
typedef __attribute__((ext_vector_type(4))) int   i32x4;

__device__ __forceinline__ unsigned short f2bf(float f) {
    unsigned u = __builtin_bit_cast(unsigned, f);
    u += 0x7FFFu + ((u >> 16) & 1u);          // RNE
    return (unsigned short)(u >> 16);
}
__device__ __forceinline__ float bf2f(unsigned short h) {
    unsigned u = ((unsigned)h) << 16;
    return __builtin_bit_cast(float, u);
}
__device__ __forceinline__ float sigmoidf_(float x) {
    return 1.f / (1.f + __expf(-x));
}
__device__ __forceinline__ float tanhf_(float x) {
    return 1.f - 2.f / (__expf(2.f * x) + 1.f);
}

// ---- weight prep: W_cell[256][128][3][3] -> Wg2[9][256][128] bf16
//                   W_seq [64][64][3][3]   -> Ws2[9][64][64]   bf16
__global__ void prep_weights_kernel(const float* __restrict__ Wc,
                                    const float* __restrict__ Ws,
                                    unsigned short* __restrict__ Wg2,
                                    unsigned short* __restrict__ Ws2) {
    int i = blockIdx.x * 256 + threadIdx.x;
    if (i < 9 * 256 * 128) {
        int tap = i >> 15, r = i & 32767, co = r >> 7, ci = r & 127;
        Wg2[i] = f2bf(Wc[(co * 128 + ci) * 9 + tap]);
    }
    if (i < 9 * 64 * 64) {
        int tap = i / 4096, r = i & 4095, co = r >> 6, ci = r & 63;
        Ws2[i] = f2bf(Ws[(co * 64 + ci) * 9 + tap]);
    }
}

// ---- seq conv, ALL timesteps in one dispatch: x fp32 CHW -> xout fp32 CHW
// grid 8192 = 8 t x 4 b x 128 y x 2 xhalf. 256 threads / 4 waves.
// All 18 weight frags preloaded to registers (no L2 traffic in MFMA loop).
__global__ __launch_bounds__(256, 2) void seq_conv_mfma(
    const float* __restrict__ xinp,           // [8][4][64][128][128]
    const unsigned short* __restrict__ Ws2,   // [9][64][64]
    const float* __restrict__ bseq,           // [64]
    float* __restrict__ xout)                 // [8][4][64][128][128]
{
    __shared__ __align__(16) unsigned short tile[3 * 66 * 72];  // 28512 B

    const int tid = threadIdx.x;
    const int sb  = (blockIdx.x & 7) * 1024 + (blockIdx.x >> 3);  // XCD swizzle
    const int t   = sb >> 10;
    const int rem = sb & 1023;
    const int b   = rem >> 8;
    const int y   = (rem >> 1) & 127;
    const int x0  = (rem & 1) * 64;

    const float* xb = xinp + (size_t)t * PLANE + (size_t)b * 64 * IMG;

    // ---- two-phase staging ----
    float4 fa[6], fb[6];
    #pragma unroll
    for (int it = 0; it < 6; ++it) {
        int i = tid + it * 256;
        int xq = i & 15, cip = (i >> 4) & 31, ry = i >> 9;
        int gy = y - 1 + ry;
        int ci = cip * 2;
        float4 va = {0.f, 0.f, 0.f, 0.f}, vb = {0.f, 0.f, 0.f, 0.f};
        if ((unsigned)gy < 128u) {
            va = *(const float4*)(xb + (size_t)ci * IMG + gy * HWDIM + x0 + xq * 4);
            vb = *(const float4*)(xb + (size_t)(ci + 1) * IMG + gy * HWDIM + x0 + xq * 4);
        }
        fa[it] = va; fb[it] = vb;
    }
    float ea = 0.f, eb = 0.f;
    {
        int e = tid & 1, cip = (tid >> 1) & 31, ry = tid >> 6;
        int xt = e ? 65 : 0;
        int gy = y - 1 + ry, gx = x0 - 1 + xt;
        int ci = cip * 2;
        if (tid < 192 && (unsigned)gy < 128u && (unsigned)gx < 128u) {
            ea = xb[(size_t)ci * IMG + gy * HWDIM + gx];
            eb = xb[(size_t)(ci + 1) * IMG + gy * HWDIM + gx];
        }
    }
    #pragma unroll
    for (int it = 0; it < 6; ++it) {
        int i = tid + it * 256;
        int xq = i & 15, cip = (i >> 4) & 31, ry = i >> 9;
        int ci = cip * 2;
        const float* pa = (const float*)&fa[it];
        const float* pb = (const float*)&fb[it];
        #pragma unroll
        for (int j = 0; j < 4; ++j) {
            unsigned pk = (unsigned)f2bf(pa[j]) | ((unsigned)f2bf(pb[j]) << 16);
            *(unsigned*)(tile + (ry * 66 + 1 + xq * 4 + j) * 72 + ci) = pk;
        }
    }
    if (tid < 192) {
        int e = tid & 1, cip = (tid >> 1) & 31, ry = tid >> 6;
        int xt = e ? 65 : 0;
        unsigned pk = (unsigned)f2bf(ea) | ((unsigned)f2bf(eb) << 16);
        *(unsigned*)(tile + (ry * 66 + xt) * 72 + cip * 2) = pk;
    }

    const int lane = tid & 63;
    const int w = tid >> 6;                 // cout stripe w*16
    const int ln = lane & 15, lg = lane >> 4;

    // ---- preload ALL weights (18 frags = 72 VGPR) ----
    const unsigned short* wbase = Ws2 + (size_t)(w * 16 + ln) * 64 + lg * 8;
    bf16x8 wreg[18];
    #pragma unroll
    for (int st = 0; st < 18; ++st) {
        int tap = st >> 1, kk = st & 1;
        wreg[st] = *(const bf16x8*)(wbase + tap * 4096 + kk * 32);
    }

    __syncthreads();

    f32x4 acc[4];
    #pragma unroll
    for (int n = 0; n < 4; ++n) acc[n] = (f32x4){0.f, 0.f, 0.f, 0.f};

    #pragma unroll
    for (int st = 0; st < 18; ++st) {
        const int tap = st >> 1, kk = st & 1;
        const int dy = tap / 3, dxx = tap % 3;
        #pragma unroll
        for (int n = 0; n < 4; ++n) {
            bf16x8 imf = *(const bf16x8*)(tile + (dy * 66 + n * 16 + ln + dxx) * 72 + kk * 32 + lg * 8);
            acc[n] = __builtin_amdgcn_mfma_f32_16x16x32_bf16(wreg[st], imf, acc[n], 0, 0, 0);
        }
    }

    // epilogue: xout fp32 CHW, coalesced (lane -> px)
    float* xout_t = xout + (size_t)t * PLANE;
    const int co = w * 16 + lg * 4;
    #pragma unroll
    for (int r = 0; r < 4; ++r) {
        const float bv = bseq[co + r];
        float* dst = xout_t + ((size_t)b * 64 + co + r) * IMG + (size_t)y * HWDIM + x0;
        #pragma unroll
        for (int n = 0; n < 4; ++n)
            dst[n * 16 + ln] = acc[n][r] + bv;
    }
}

// ---- gates conv (Cin=128 -> 256 gate-striped) + in-register LSTM epilogue
// 256 threads / 4 waves. Input ch0..63 staged from xout fp32, ch64..127 from
// bf16 HWC h buffer. Per-tap weight batches (16 frags) double-buffered.
__global__ __launch_bounds__(256, 2) void gates_lstm_mfma(
    const float* __restrict__ xo,             // xout_t [4][64][128][128] fp32
    const unsigned short* __restrict__ hin,   // [4][128][128][64] bf16
    const unsigned short* __restrict__ Wg2,   // [9][256][128]
    const float* __restrict__ bcell,          // [256]
    unsigned short* __restrict__ hout,        // [4][128][128][64] bf16
    unsigned short* __restrict__ cbuf,        // [4][128][128][64] bf16 in/out
    float* __restrict__ h32)                  // h_final fp32 CHW (t=7) or null
{
    __shared__ __align__(16) unsigned short tile[3 * 66 * 136];  // 53856 B

    const int tid = threadIdx.x;
    const int bid = (blockIdx.x & 7) * 128 + (blockIdx.x >> 3);  // XCD swizzle
    const int b  = bid >> 8;
    const int y  = (bid >> 1) & 127;
    const int x0 = (bid & 1) * 64;

    // ---- staging loads (all issued before any ds_write) ----
    const float* xb = xo + (size_t)b * 64 * IMG;
    float4 fa[6], fb[6];
    #pragma unroll
    for (int it = 0; it < 6; ++it) {
        int i = tid + it * 256;
        int xq = i & 15, cip = (i >> 4) & 31, ry = i >> 9;
        int gy = y - 1 + ry;
        int ci = cip * 2;
        float4 va = {0.f, 0.f, 0.f, 0.f}, vb = {0.f, 0.f, 0.f, 0.f};
        if ((unsigned)gy < 128u) {
            va = *(const float4*)(xb + (size_t)ci * IMG + gy * HWDIM + x0 + xq * 4);
            vb = *(const float4*)(xb + (size_t)(ci + 1) * IMG + gy * HWDIM + x0 + xq * 4);
        }
        fa[it] = va; fb[it] = vb;
    }
    float ea = 0.f, eb2 = 0.f;
    {
        int e = tid & 1, cip = (tid >> 1) & 31, ry = tid >> 6;
        int xt = e ? 65 : 0;
        int gy = y - 1 + ry, gx = x0 - 1 + xt;
        int ci = cip * 2;
        if (tid < 192 && (unsigned)gy < 128u && (unsigned)gx < 128u) {
            ea  = xb[(size_t)ci * IMG + gy * HWDIM + gx];
            eb2 = xb[(size_t)(ci + 1) * IMG + gy * HWDIM + gx];
        }
    }
    const unsigned short* hb = hin + (size_t)b * 128 * 128 * 64;
    i32x4 hv[6];
    #pragma unroll
    for (int it = 0; it < 6; ++it) {
        int i = tid + it * 256;          // (ry*64 + xtm)*8 + g ; xt = xtm+1
        int g = i & 7, xtm = (i >> 3) & 63, ry = i >> 9;
        int gy = y - 1 + ry, gx = x0 + xtm;   // in [0,128) always
        i32x4 v = {0, 0, 0, 0};
        if ((unsigned)gy < 128u)
            v = *(const i32x4*)(hb + ((size_t)gy * 128 + gx) * 64 + g * 8);
        hv[it] = v;
    }
    i32x4 he = {0, 0, 0, 0};
    {
        int g = tid & 7, e = (tid >> 3) & 1, ry = tid >> 4;
        int xt = e ? 65 : 0;
        int gy = y - 1 + ry, gx = x0 - 1 + xt;
        if (tid < 48 && (unsigned)gy < 128u && (unsigned)gx < 128u)
            he = *(const i32x4*)(hb + ((size_t)gy * 128 + gx) * 64 + g * 8);
    }

    // ---- ds_writes ----
    #pragma unroll
    for (int it = 0; it < 6; ++it) {
        int i = tid + it * 256;
        int xq = i & 15, cip = (i >> 4) & 31, ry = i >> 9;
        int ci = cip * 2;
        const float* pa = (const float*)&fa[it];
        const float* pb = (const float*)&fb[it];
        #pragma unroll
        for (int j = 0; j < 4; ++j) {
            unsigned pk = (unsigned)f2bf(pa[j]) | ((unsigned)f2bf(pb[j]) << 16);
            *(unsigned*)(tile + (ry * 66 + 1 + xq * 4 + j) * 136 + ci) = pk;
        }
    }
    if (tid < 192) {
        int e = tid & 1, cip = (tid >> 1) & 31, ry = tid >> 6;
        int xt = e ? 65 : 0;
        unsigned pk = (unsigned)f2bf(ea) | ((unsigned)f2bf(eb2) << 16);
        *(unsigned*)(tile + (ry * 66 + xt) * 136 + cip * 2) = pk;
    }
    #pragma unroll
    for (int it = 0; it < 6; ++it) {
        int i = tid + it * 256;
        int g = i & 7, xtm = (i >> 3) & 63, ry = i >> 9;
        *(i32x4*)(tile + (ry * 66 + 1 + xtm) * 136 + 64 + g * 8) = hv[it];
    }
    if (tid < 48) {
        int g = tid & 7, e = (tid >> 3) & 1, ry = tid >> 4;
        int xt = e ? 65 : 0;
        *(i32x4*)(tile + (ry * 66 + xt) * 136 + 64 + g * 8) = he;
    }

    // ---- prefetch weight taps 0,1 (issued before barrier) ----
    const int lane = tid & 63;
    const int w = tid >> 6;                 // cout stripe (within each gate)
    const int ln = lane & 15, lg = lane >> 4;
    const int s = w * 16;
    const unsigned short* wbase = Wg2 + (size_t)(s + ln) * 128 + lg * 8;

    bf16x8 w0[4][4], w1[4][4];              // [g][kk]
    auto WLOADT = [&](bf16x8 (&wf)[4][4], int tap) {
        #pragma unroll
        for (int g = 0; g < 4; ++g)
            #pragma unroll
            for (int kk = 0; kk < 4; ++kk)
                wf[g][kk] = *(const bf16x8*)(wbase + tap * 32768 + g * 8192 + kk * 32);
    };
    WLOADT(w0, 0);
    WLOADT(w1, 1);

    __syncthreads();

    f32x4 acc[4][4];                        // [m_px][gate]
    #pragma unroll
    for (int m = 0; m < 4; ++m)
        #pragma unroll
        for (int g = 0; g < 4; ++g) acc[m][g] = (f32x4){0.f, 0.f, 0.f, 0.f};

    auto MSTEP = [&](bf16x8 (&wf)[4][4], int tap) {
        const int dy = tap / 3, dxx = tap % 3;
        #pragma unroll
        for (int kk = 0; kk < 4; ++kk) {
            #pragma unroll
            for (int m = 0; m < 4; ++m) {
                bf16x8 af = *(const bf16x8*)(tile + (dy * 66 + m * 16 + ln + dxx) * 136 + kk * 32 + lg * 8);
                #pragma unroll
                for (int g = 0; g < 4; ++g)
                    acc[m][g] = __builtin_amdgcn_mfma_f32_16x16x32_bf16(af, wf[g][kk], acc[m][g], 0, 0, 0);
            }
        }
    };

    MSTEP(w0, 0); WLOADT(w0, 2);
    MSTEP(w1, 1); WLOADT(w1, 3);
    MSTEP(w0, 2); WLOADT(w0, 4);
    MSTEP(w1, 3); WLOADT(w1, 5);
    MSTEP(w0, 4); WLOADT(w0, 6);
    MSTEP(w1, 5); WLOADT(w1, 7);
    MSTEP(w0, 6); WLOADT(w0, 8);
    MSTEP(w1, 7);
    MSTEP(w0, 8);

    // ---- in-register LSTM pointwise: lane owns ch = s+ln, px = m*16+lg*4+r
    const int ch = s + ln;
    const float bi = bcell[ch], bf_ = bcell[64 + ch];
    const float bg = bcell[128 + ch], bo = bcell[192 + ch];

    #pragma unroll
    for (int m = 0; m < 4; ++m) {
        #pragma unroll
        for (int r = 0; r < 4; ++r) {
            const int px = m * 16 + lg * 4 + r;
            float gi = acc[m][0][r] + bi;
            float gf = acc[m][1][r] + bf_;
            float gg = acc[m][2][r] + bg;
            float go = acc[m][3][r] + bo;
            float si = sigmoidf_(gi);
            float sf = sigmoidf_(gf);
            float tg = tanhf_(gg);
            float so = sigmoidf_(go);
            const size_t pixbase = ((size_t)b * 128 + y) * 128 + x0 + px;
            const size_t cidx = pixbase * 64 + ch;
            float cold = bf2f(cbuf[cidx]);
            float cn = sf * cold + si * tg;
            cbuf[cidx] = f2bf(cn);
            float hv2 = so * tanhf_(cn);
            hout[cidx] = f2bf(hv2);
            if (h32) h32[((size_t)b * 64 + ch) * IMG + (size_t)y * HWDIM + x0 + px] = hv2;
        }
    }
}

extern "C" void kernel_launch(void* const* d_in, const int* in_sizes, int n_in,
                              void* d_out, int out_size, void* d_ws, size_t ws_size,
                              hipStream_t stream) {
    const float* xinp   = (const float*)d_in[0]; // [8,4,64,128,128]
    const float* W_seq  = (const float*)d_in[1];
    const float* b_seq  = (const float*)d_in[2];
    const float* W_cell = (const float*)d_in[3];
    const float* b_cell = (const float*)d_in[4];

    float* out     = (float*)d_out;
    float* h_final = out;                    // [4,64,128,128] fp32
    float* xout    = out + PLANE;            // [8,4,64,128,128] fp32

    // ws (bf16 elems): c | h0 | h1 | Wg2 | Ws2   (~25.8 MB)
    unsigned short* cbuf = (unsigned short*)d_ws;
    unsigned short* hb0  = cbuf + PLANE;
    unsigned short* hb1  = hb0 + PLANE;
    unsigned short* Wg2  = hb1 + PLANE;
    unsigned short* Ws2  = Wg2 + 9 * 256 * 128;
    unsigned short* hbufs[2] = { hb0, hb1 };

    hipMemsetAsync(hb0,  0, (size_t)PLANE * sizeof(unsigned short), stream); // h0
    hipMemsetAsync(cbuf, 0, (size_t)PLANE * sizeof(unsigned short), stream); // c0

    prep_weights_kernel<<<1152, 256, 0, stream>>>(W_cell, W_seq, Wg2, Ws2);

    // all 8 timesteps' seq convs in one dispatch (independent of recurrence)
    seq_conv_mfma<<<8192, 256, 0, stream>>>(xinp, Ws2, b_seq, xout);

    for (int t = 0; t < 8; ++t) {
        gates_lstm_mfma<<<1024, 256, 0, stream>>>(
            xout + (size_t)t * PLANE, hbufs[t & 1], Wg2, b_cell,
            hbufs[(t + 1) & 1], cbuf,
            (t == 7) ? h_final : (float*)nullptr);
    }
}